// Round 3
// baseline (377.806 us; speedup 1.0000x reference)
//
#include <hip/hip_runtime.h>

// ExtractGraph: maxpool(2x2) -> threshold=(max-min)/96 -> d=pool+noise ->
// diagonal-neighbor adjacency (|diff|<=thr), symmetric -> & dropout_mask ->
// row-major COO edge list padded with sentinel NUM_NODES.
//
// R3: SINGLE kernel, 9 blocks x 1024 threads (one node per thread).
//  - Threshold: every block redundantly pools all 147KB of d_coarse into its
//    own LDS and reduces min/max locally -> no cross-block reduction at all
//    (max/min are order-independent -> bit-exact).
//  - Edge placement: forward-only decoupled lookback over 9 blocks using
//    agent-scope atomics (blocks spin ONLY on predecessors -> deadlock-free
//    even under serialized dispatch; agent scope handles XCD L2s).
//    "valid" flag = bit30; harness ws poison 0xAAAAAAAA has bit30 CLEAR.
//  - Sentinel tail: last block (knows total) fills [total, MAX_EDGES).

#define HW 192
#define MM 96
#define NUM_NODES 9216
#define MAX_EDGES 36864
#define NBLK 9
#define BT 1024
#define VALID_BIT 0x40000000

__global__ __launch_bounds__(BT) void extract_graph(
    const float* __restrict__ dc,     // [192*192]
    const float* __restrict__ noise,  // [96*96]
    const int*   __restrict__ mask,   // [9216*9216] bool-as-int32
    int*         __restrict__ out,    // [2*36864]
    int*         __restrict__ blk_state) // [NBLK] in ws, poisoned 0xAAAAAAAA
{
    __shared__ float d_lds[NUM_NODES];
    __shared__ float smx[16], smn[16];
    __shared__ int   wsum[16];
    __shared__ float s_thr;
    __shared__ int   s_blkoff, s_btot;

    const int t = threadIdx.x;
    const int b = blockIdx.x;
    const int lane = t & 63, wid = t >> 6;

    // ---- Phase 1: full redundant pool+noise into LDS; local min/max ----
    float vmax = -3.0e38f, vmin = 3.0e38f;
    #pragma unroll
    for (int k = 0; k < NUM_NODES / BT; ++k) {
        int l = k * BT + t;
        int i = l / MM, j = l - i * MM;
        const float* r0 = dc + (2 * i) * HW + 2 * j;
        float2 a = *(const float2*)r0;
        float2 c = *(const float2*)(r0 + HW);
        float p = fmaxf(fmaxf(a.x, a.y), fmaxf(c.x, c.y));
        vmax = fmaxf(vmax, p);
        vmin = fminf(vmin, p);
        d_lds[l] = p + noise[l];
    }
    #pragma unroll
    for (int off = 32; off > 0; off >>= 1) {
        vmax = fmaxf(vmax, __shfl_down(vmax, off, 64));
        vmin = fminf(vmin, __shfl_down(vmin, off, 64));
    }
    if (lane == 0) { smx[wid] = vmax; smn[wid] = vmin; }
    __syncthreads();
    if (t == 0) {
        float mx = smx[0], mn = smn[0];
        #pragma unroll
        for (int k = 1; k < 16; ++k) {
            mx = fmaxf(mx, smx[k]);
            mn = fminf(mn, smn[k]);
        }
        s_thr = (mx - mn) / 96.0f;
    }
    __syncthreads();
    const float thr = s_thr;

    // ---- Phase 2: per-node neighbor flags (ascending col: -97,-95,+95,+97) ----
    const int l = b * BT + t;
    const int i = l / MM, j = l - i * MM;
    const float dl = d_lds[l];
    const size_t rowbase = (size_t)l * NUM_NODES;
    int f = 0;
    if (i > 0) {
        if (j > 0      && fabsf(d_lds[l - 97] - dl) <= thr && mask[rowbase + (l - 97)]) f |= 1;
        if (j < MM - 1 && fabsf(d_lds[l - 95] - dl) <= thr && mask[rowbase + (l - 95)]) f |= 2;
    }
    if (i < MM - 1) {
        if (j > 0      && fabsf(d_lds[l + 95] - dl) <= thr && mask[rowbase + (l + 95)]) f |= 4;
        if (j < MM - 1 && fabsf(d_lds[l + 97] - dl) <= thr && mask[rowbase + (l + 97)]) f |= 8;
    }
    const int cnt = __popc(f);

    // ---- Phase 3: block scan (wave shuffle + cross-wave LDS) ----
    int inc = cnt;
    #pragma unroll
    for (int off = 1; off < 64; off <<= 1) {
        int v = __shfl_up(inc, off, 64);
        if (lane >= off) inc += v;
    }
    if (lane == 63) wsum[wid] = inc;
    __syncthreads();
    int wpre = 0;
    for (int k = 0; k < wid; ++k) wpre += wsum[k];
    const int local_excl = wpre + inc - cnt;

    // ---- Phase 4: publish count; forward lookback over predecessors ----
    if (wid == 0) {
        if (lane == 0) {
            int btot = 0;
            #pragma unroll
            for (int k = 0; k < 16; ++k) btot += wsum[k];
            s_btot = btot;
            __hip_atomic_store(&blk_state[b], VALID_BIT | btot,
                               __ATOMIC_RELEASE, __HIP_MEMORY_SCOPE_AGENT);
        }
        int v = 0;
        if (lane < b) {   // spin only on PREDECESSORS -> deadlock-free
            int s;
            do {
                s = __hip_atomic_load(&blk_state[lane],
                                      __ATOMIC_ACQUIRE, __HIP_MEMORY_SCOPE_AGENT);
            } while (!(s & VALID_BIT));
            v = s & 0xFFFF;
        }
        #pragma unroll
        for (int off = 32; off > 0; off >>= 1) v += __shfl_down(v, off, 64);
        if (lane == 0) s_blkoff = v;
    }
    __syncthreads();

    // ---- Phase 5: write edges in exact row-major order ----
    int pos = s_blkoff + local_excl;
    if (f & 1) { out[pos] = l; out[MAX_EDGES + pos] = l - 97; ++pos; }
    if (f & 2) { out[pos] = l; out[MAX_EDGES + pos] = l - 95; ++pos; }
    if (f & 4) { out[pos] = l; out[MAX_EDGES + pos] = l + 95; ++pos; }
    if (f & 8) { out[pos] = l; out[MAX_EDGES + pos] = l + 97; ++pos; }

    // ---- Phase 6: last block fills sentinel tail ----
    if (b == NBLK - 1) {
        const int total = s_blkoff + s_btot;
        for (int idx = total + t; idx < MAX_EDGES; idx += BT) {
            out[idx] = NUM_NODES;
            out[MAX_EDGES + idx] = NUM_NODES;
        }
    }
}

extern "C" void kernel_launch(void* const* d_in, const int* in_sizes, int n_in,
                              void* d_out, int out_size, void* d_ws, size_t ws_size,
                              hipStream_t stream) {
    const float* d_coarse = (const float*)d_in[0];
    const float* noise    = (const float*)d_in[1];
    const int*   mask     = (const int*)d_in[2];
    int* out       = (int*)d_out;
    int* blk_state = (int*)d_ws;   // poisoned to 0xAAAAAAAA (bit30 clear) pre-launch

    extract_graph<<<NBLK, BT, 0, stream>>>(d_coarse, noise, mask, out, blk_state);
}